// Round 6
// baseline (619.878 us; speedup 1.0000x reference)
//
#include <hip/hip_runtime.h>
#include <hip/hip_bf16.h>

typedef __bf16 bf16;
typedef __attribute__((ext_vector_type(8))) __bf16 bf16x8;
typedef __attribute__((ext_vector_type(4))) __bf16 bf16x4;
typedef __attribute__((ext_vector_type(4))) float f32x4;

// Problem constants: N=4, T=S=4096, D=256, causal, single head.

static __device__ __forceinline__ unsigned swz(unsigned off, unsigned row) {
  return off ^ ((row & 7u) << 4);
}

// ---------------------------------------------------------------------------
// Input-dtype detector (wave-parallel): bf16 pairs vs fp32 words.
// ---------------------------------------------------------------------------
__global__ void detect_dtype_kernel(const unsigned* __restrict__ q, int* __restrict__ flag) {
  int t = threadIdx.x;  // 64 threads
  int cnt = 0;
  for (int i = t; i < 256; i += 64) {
    unsigned ex = (q[i] >> 7) & 0xFFu;
    cnt += (ex >= 100u && ex <= 140u) ? 1 : 0;
  }
  #pragma unroll
  for (int off = 32; off; off >>= 1) cnt += __shfl_down(cnt, off);
  if (t == 0) *flag = (cnt >= 200) ? 1 : 0;
}

// ---------------------------------------------------------------------------
// Projection GEMM: out = X @ W^T + b. 64x64 tile, K in 4 chunks of 64 with
// reg-staged async split (T14): chunk kc+1's global loads issue before chunk
// kc's MFMA. LDS 16KB (was 64KB) -> 4 blocks/CU. Q pre-scaled by log2e/sqrt(D);
// V written transposed Vt[n][d][s].
// ---------------------------------------------------------------------------
__global__ __launch_bounds__(256, 4) void proj_kernel(
    const void* __restrict__ xq, const void* __restrict__ xk, const void* __restrict__ xv,
    const void* __restrict__ Wq, const void* __restrict__ bq,
    const void* __restrict__ Wk, const void* __restrict__ bk,
    const void* __restrict__ Wv, const void* __restrict__ bv,
    bf16* __restrict__ Qo, bf16* __restrict__ Ko, bf16* __restrict__ Vt,
    const int* __restrict__ flagp)
{
  const int proj = blockIdx.z;
  const void* X  = proj == 0 ? xq : (proj == 1 ? xk : xv);
  const void* W  = proj == 0 ? Wq : (proj == 1 ? Wk : Wv);
  const void* Bp = proj == 0 ? bq : (proj == 1 ? bk : bv);
  const int i0 = blockIdx.x * 64;
  const int j0 = blockIdx.y * 64;
  const int isbf = *flagp;

  __shared__ __align__(16) char lds[16384];
  char* A_lds = lds;         // 64 x 64 bf16 = 8KB, swizzled, row stride 128B
  char* W_lds = lds + 8192;
  const int t = threadIdx.x;

  f32x4 af32[4], wf32[4];
  bf16x8 ab16[2], wb16[2];

  auto load_chunk = [&](int kc) {
    if (isbf) {
      #pragma unroll
      for (int i = 0; i < 2; ++i) {
        int cidx = t + i * 256;
        int row = cidx >> 3, c8 = cidx & 7;
        ab16[i] = *(const bf16x8*)((const char*)X + ((size_t)(i0 + row) << 9) + (kc << 7) + (c8 << 4));
        wb16[i] = *(const bf16x8*)((const char*)W + ((size_t)(j0 + row) << 9) + (kc << 7) + (c8 << 4));
      }
    } else {
      #pragma unroll
      for (int i = 0; i < 4; ++i) {
        int cidx = t + i * 256;
        int row = cidx >> 4, c4 = cidx & 15;
        af32[i] = *(const f32x4*)((const char*)X + ((size_t)(i0 + row) << 10) + (kc << 8) + (c4 << 4));
        wf32[i] = *(const f32x4*)((const char*)W + ((size_t)(j0 + row) << 10) + (kc << 8) + (c4 << 4));
      }
    }
  };
  auto write_chunk = [&]() {
    if (isbf) {
      #pragma unroll
      for (int i = 0; i < 2; ++i) {
        int cidx = t + i * 256;
        int row = cidx >> 3, c8 = cidx & 7;
        *(bf16x8*)(A_lds + swz((unsigned)((row << 7) + (c8 << 4)), (unsigned)row)) = ab16[i];
        *(bf16x8*)(W_lds + swz((unsigned)((row << 7) + (c8 << 4)), (unsigned)row)) = wb16[i];
      }
    } else {
      #pragma unroll
      for (int i = 0; i < 4; ++i) {
        int cidx = t + i * 256;
        int row = cidx >> 4, c4 = cidx & 15;
        bf16x4 ha = { (bf16)af32[i][0], (bf16)af32[i][1], (bf16)af32[i][2], (bf16)af32[i][3] };
        bf16x4 hw = { (bf16)wf32[i][0], (bf16)wf32[i][1], (bf16)wf32[i][2], (bf16)wf32[i][3] };
        *(bf16x4*)(A_lds + swz((unsigned)((row << 7) + (c4 << 3)), (unsigned)row)) = ha;
        *(bf16x4*)(W_lds + swz((unsigned)((row << 7) + (c4 << 3)), (unsigned)row)) = hw;
      }
    }
  };

  const int w = t >> 6, l = t & 63, lr = l & 15, lhi = l >> 4;
  const int arow = w * 16 + lr;
  f32x4 acc[4] = {};

  load_chunk(0);
  for (int kc = 0; kc < 4; ++kc) {
    write_chunk();
    if (kc < 3) load_chunk(kc + 1);
    __syncthreads();
    #pragma unroll
    for (int kk = 0; kk < 2; ++kk) {
      bf16x8 af = *(const bf16x8*)(A_lds + swz((unsigned)((arow << 7) + (kk << 6) + (lhi << 4)), (unsigned)arow));
      #pragma unroll
      for (int cb = 0; cb < 4; ++cb) {
        int brow = cb * 16 + lr;
        bf16x8 wf = *(const bf16x8*)(W_lds + swz((unsigned)((brow << 7) + (kk << 6) + (lhi << 4)), (unsigned)brow));
        acc[cb] = __builtin_amdgcn_mfma_f32_16x16x32_bf16(af, wf, acc[cb], 0, 0, 0);
      }
    }
    __syncthreads();
  }

  const float QSCALE = 0.09016844005555646f;  // log2(e) / sqrt(256)
  for (int cb = 0; cb < 4; ++cb) {
    int j = j0 + cb * 16 + lr;
    float bias = isbf ? (float)((const bf16*)Bp)[j] : ((const float*)Bp)[j];
    for (int r = 0; r < 4; ++r) {
      int i = i0 + w * 16 + lhi * 4 + r;   // C layout: col=lane&15, row=(lane>>4)*4+r
      float val = acc[cb][r] + bias;
      if (proj == 0) {
        Qo[((size_t)i << 8) + j] = (bf16)(val * QSCALE);
      } else if (proj == 1) {
        Ko[((size_t)i << 8) + j] = (bf16)val;
      } else {
        int n = i >> 12, s = i & 4095;
        Vt[((size_t)n << 20) + ((size_t)j << 12) + s] = (bf16)val;
      }
    }
  }
}

// ---------------------------------------------------------------------------
// Split-KV flash attention (causal), ~uniform 24-tile (768-KV) chunks:
// nc(qi) = ceil((qi+1)/12) -> 204 blocks/batch, 816 total. Reg-staged async
// K/V staging (T14): next tile's loads issued before current tile's compute.
// Writes normalized partial O (bf16) + per-row w = m + log2(l).
// ---------------------------------------------------------------------------
__global__ __launch_bounds__(256, 3) void attn_kernel(
    const bf16* __restrict__ Q, const bf16* __restrict__ K,
    const bf16* __restrict__ Vt, bf16* __restrict__ Opart, float* __restrict__ wrow)
{
  __shared__ __align__(16) char lds[36864];
  char* K_lds  = lds;            // 32 x 256 bf16 = 16KB (swizzled)
  char* V_lds  = lds + 16384;    // 256 x 32 bf16 = 16KB (Vt layout, swizzled)
  char* P_base = lds + 32768;    // 4 waves x 1KB

  const int n  = blockIdx.y;
  // bijective XCD swizzle over 204 = 8*25+4 (m204 variant)
  const int bx  = blockIdx.x;
  const int xcd = bx & 7, idx = bx >> 3;
  const int e   = (xcd < 4 ? xcd * 26 : 104 + (xcd - 4) * 25) + idx;
  int g = 0;
  #pragma unroll
  for (int gg = 1; gg <= 5; ++gg) if (e >= 6 * gg * (gg + 1)) g = gg;
  const int r_   = e - 6 * g * (g + 1);
  const int nc   = g + 1;
  const int qoff = r_ / nc;
  const int qi   = 12 * g + qoff;
  const int c    = r_ - qoff * nc;
  const int q0   = qi * 64;
  const int t32  = (qi + 1) * 2;            // 32-wide KV tiles for this q-tile
  const int it0  = c * t32 / nc, it1 = (c + 1) * t32 / nc;

  const int t = threadIdx.x, w = t >> 6, l = t & 63, lr = l & 15, lhi = l >> 4;
  const bf16* Qb = Q  + ((size_t)n << 20);
  const bf16* Kb = K  + ((size_t)n << 20);
  const bf16* Vb = Vt + ((size_t)n << 20);
  char* myP = P_base + (w << 10);

  // per-thread staging offsets (constant across iterations)
  unsigned gofK[4], lofK[4], gofV[4], lofV[4];
  #pragma unroll
  for (int i = 0; i < 4; ++i) {
    int cidx = t + i * 256;
    int row = cidx >> 5, koff = (cidx & 31) << 4;
    gofK[i] = (unsigned)((row << 9) + koff);
    lofK[i] = swz((unsigned)((row << 9) + koff), (unsigned)row);
    int d = cidx >> 2, soff = (cidx & 3) << 4;
    gofV[i] = (unsigned)((d << 13) + soff);
    lofV[i] = swz((unsigned)((d << 6) + soff), (unsigned)d);
  }
  bf16x8 kst[4], vst[4];
  auto stage_load = [&](int s0) {
    #pragma unroll
    for (int i = 0; i < 4; ++i)
      kst[i] = *(const bf16x8*)((const char*)Kb + (unsigned)(s0 << 9) + gofK[i]);
    #pragma unroll
    for (int i = 0; i < 4; ++i)
      vst[i] = *(const bf16x8*)((const char*)Vb + (unsigned)(s0 << 1) + gofV[i]);
  };

  bf16x8 qf[8];
  {
    int qrow = q0 + w * 16 + lr;
    #pragma unroll
    for (int kb = 0; kb < 8; ++kb)
      qf[kb] = *(const bf16x8*)((const char*)Qb + ((size_t)qrow << 9) + (kb << 6) + (lhi << 4));
  }
  f32x4 o[16] = {};
  float m[4]    = { -3e38f, -3e38f, -3e38f, -3e38f };
  float lsum[4] = { 0.f, 0.f, 0.f, 0.f };

  stage_load(it0 << 5);
  for (int it = it0; it < it1; ++it) {
    // write staged regs -> LDS, then issue next tile's loads (overlap compute)
    #pragma unroll
    for (int i = 0; i < 4; ++i) *(bf16x8*)(K_lds + lofK[i]) = kst[i];
    #pragma unroll
    for (int i = 0; i < 4; ++i) *(bf16x8*)(V_lds + lofV[i]) = vst[i];
    if (it + 1 < it1) stage_load((it + 1) << 5);
    __syncthreads();

    const int s0 = it << 5;
    // S = Q K^T (16x32 per wave), scale folded into Q (base-2)
    f32x4 sacc[2];
    #pragma unroll
    for (int cb = 0; cb < 2; ++cb) {
      f32x4 a = {};
      #pragma unroll
      for (int kb = 0; kb < 8; ++kb) {
        int srow = cb * 16 + lr;
        bf16x8 kf = *(const bf16x8*)(K_lds + swz((unsigned)((srow << 9) + (kb << 6) + (lhi << 4)), (unsigned)srow));
        a = __builtin_amdgcn_mfma_f32_16x16x32_bf16(qf[kb], kf, a, 0, 0, 0);
      }
      sacc[cb] = a;
    }

    // causal mask near the diagonal band only
    if (s0 + 31 > q0 + w * 16) {
      #pragma unroll
      for (int cb = 0; cb < 2; ++cb)
        for (int r = 0; r < 4; ++r) {
          int s_ = s0 + cb * 16 + lr;
          int q_ = q0 + w * 16 + lhi * 4 + r;
          if (s_ > q_) sacc[cb][r] = -3e38f;
        }
    }

    // online softmax (base 2), wave-parallel 16-group reduce
    float pm[4];
    #pragma unroll
    for (int r = 0; r < 4; ++r) pm[r] = fmaxf(sacc[0][r], sacc[1][r]);
    #pragma unroll
    for (int off = 1; off < 16; off <<= 1)
      for (int r = 0; r < 4; ++r) pm[r] = fmaxf(pm[r], __shfl_xor(pm[r], off));

    // defer-max (T13): rescale only when a row max grew past m+8 (log2 units)
    unsigned long long need = __ballot((pm[0] > m[0] + 8.f) | (pm[1] > m[1] + 8.f) |
                                       (pm[2] > m[2] + 8.f) | (pm[3] > m[3] + 8.f));
    if (need) {
      float alpha[4];
      #pragma unroll
      for (int r = 0; r < 4; ++r) {
        float mn = fmaxf(m[r], pm[r]);
        alpha[r] = exp2f(m[r] - mn);
        m[r] = mn;
        lsum[r] *= alpha[r];
      }
      #pragma unroll
      for (int db = 0; db < 16; ++db)
        for (int r = 0; r < 4; ++r) o[db][r] *= alpha[r];
    }

    float ps[4] = {};
    #pragma unroll
    for (int cb = 0; cb < 2; ++cb)
      for (int r = 0; r < 4; ++r) {
        float p = exp2f(sacc[cb][r] - m[r]);
        sacc[cb][r] = p;
        ps[r] += p;
      }
    #pragma unroll
    for (int off = 1; off < 16; off <<= 1)
      for (int r = 0; r < 4; ++r) ps[r] += __shfl_xor(ps[r], off);
    #pragma unroll
    for (int r = 0; r < 4; ++r) lsum[r] += ps[r];

    // P (C layout) -> per-wave LDS tile -> A-fragment layout
    #pragma unroll
    for (int cb = 0; cb < 2; ++cb)
      for (int r = 0; r < 4; ++r) {
        int prow = lhi * 4 + r, pcol = cb * 16 + lr;
        *(bf16*)(myP + swz((unsigned)((prow << 6) + (pcol << 1)), (unsigned)prow)) = (bf16)sacc[cb][r];
      }
    asm volatile("s_waitcnt lgkmcnt(0)" ::: "memory");
    __builtin_amdgcn_sched_barrier(0);

    bf16x8 pf = *(const bf16x8*)(myP + swz((unsigned)((lr << 6) + (lhi << 4)), (unsigned)lr));
    #pragma unroll
    for (int db = 0; db < 16; ++db) {
      int drow = db * 16 + lr;
      bf16x8 vf = *(const bf16x8*)(V_lds + swz((unsigned)((drow << 6) + (lhi << 4)), (unsigned)drow));
      o[db] = __builtin_amdgcn_mfma_f32_16x16x32_bf16(pf, vf, o[db], 0, 0, 0);
    }
    __syncthreads();
  }

  // epilogue: normalized partial (bf16) + per-row combine weight w = m + log2(l)
  float invl[4];
  #pragma unroll
  for (int r = 0; r < 4; ++r) invl[r] = 1.f / lsum[r];
  bf16* Ob = Opart + (size_t)(n * 204 + e) * 16384;
  for (int db = 0; db < 16; ++db) {
    int col = db * 16 + lr;
    for (int r = 0; r < 4; ++r) {
      int row = w * 16 + lhi * 4 + r;
      Ob[row * 256 + col] = (bf16)(o[db][r] * invl[r]);
    }
  }
  if (lr == 0) {
    #pragma unroll
    for (int r = 0; r < 4; ++r) {
      int row = w * 16 + lhi * 4 + r;
      wrow[(n * 204 + e) * 64 + row] = m[r] + log2f(lsum[r]);
    }
  }
}

// ---------------------------------------------------------------------------
// Combine: out = sum_i 2^(w_i - W*) o_i / sum_i 2^(w_i - W*). Block handles
// 16 q-rows; grid (256, 4) = 1024 blocks (4/CU).
// ---------------------------------------------------------------------------
__global__ __launch_bounds__(256) void combine_kernel(
    const bf16* __restrict__ Opart, const float* __restrict__ wrow,
    float* __restrict__ out)
{
  const int bx = blockIdx.x, n = blockIdx.y;
  const int qi = bx >> 2, rowbase = (bx & 3) << 4;
  const int g  = qi / 12;                    // 0..5
  const int nc = g + 1;
  const int off = 6 * g * (g + 1) + (qi - 12 * g) * nc;
  const int t = threadIdx.x;
  const int row  = rowbase + (t >> 4);       // tile-local q-row
  const int col0 = (t & 15) << 4;            // 16 cols per thread
  const size_t pbase = (size_t)(n * 204 + off);

  float u[6];
  float Wm = -3e38f;
  #pragma unroll
  for (int i = 0; i < 6; ++i) {
    u[i] = (i < nc) ? wrow[(pbase + i) * 64 + row] : -3e38f;
    Wm = fmaxf(Wm, u[i]);
  }
  float denom = 0.f;
  #pragma unroll
  for (int i = 0; i < 6; ++i) { u[i] = (i < nc) ? exp2f(u[i] - Wm) : 0.f; denom += u[i]; }
  float inv = 1.f / denom;

  float a[16] = {};
  #pragma unroll
  for (int i = 0; i < 6; ++i) {
    if (i < nc) {
      float ui = u[i] * inv;
      const bf16* p = Opart + (pbase + i) * 16384 + row * 256 + col0;
      bf16x8 v0 = *(const bf16x8*)(p);
      bf16x8 v1 = *(const bf16x8*)(p + 8);
      #pragma unroll
      for (int j = 0; j < 8; ++j) { a[j] += ui * (float)v0[j]; a[8 + j] += ui * (float)v1[j]; }
    }
  }
  float* op = out + ((size_t)n << 20) + ((size_t)(qi * 64 + row) << 8) + col0;
  #pragma unroll
  for (int j2 = 0; j2 < 4; ++j2) {
    f32x4 vv = { a[j2 * 4], a[j2 * 4 + 1], a[j2 * 4 + 2], a[j2 * 4 + 3] };
    *(f32x4*)(op + j2 * 4) = vv;
  }
}

extern "C" void kernel_launch(void* const* d_in, const int* in_sizes, int n_in,
                              void* d_out, int out_size, void* d_ws, size_t ws_size,
                              hipStream_t stream) {
  const void* q_in = d_in[0];
  const void* k_in = d_in[1];
  const void* v_in = d_in[2];
  // d_in[3] = attn_mask: causal tril, hardcoded
  const void* Wq = d_in[4]; const void* bq = d_in[5];
  const void* Wk = d_in[6]; const void* bk = d_in[7];
  const void* Wv = d_in[8]; const void* bv = d_in[9];

  char* ws = (char*)d_ws;
  bf16*  Qw    = (bf16*)(ws);                              // 8 MB
  bf16*  Kw    = (bf16*)(ws + (size_t)(8  << 20));         // 8 MB
  bf16*  Vtw   = (bf16*)(ws + (size_t)(16 << 20));         // 8 MB, [n][d][s]
  int*   flag  = (int*) (ws + (size_t)(24 << 20));         // 4 B
  float* wrow  = (float*)(ws + (size_t)(24 << 20) + 4096); // 4*204*64*4 = 209 KB
  bf16*  Opart = (bf16*)(ws + (size_t)(25 << 20));         // 4*204*32KB = 26.7 MB

  detect_dtype_kernel<<<1, 64, 0, stream>>>((const unsigned*)q_in, flag);
  proj_kernel<<<dim3(256, 4, 3), 256, 0, stream>>>(q_in, k_in, v_in,
                                                   Wq, bq, Wk, bk, Wv, bv,
                                                   Qw, Kw, Vtw, flag);
  attn_kernel<<<dim3(204, 4), 256, 0, stream>>>(Qw, Kw, Vtw, Opart, wrow);
  combine_kernel<<<dim3(256, 4), 256, 0, stream>>>(Opart, wrow, (float*)d_out);
}

// Round 14
// 347.066 us; speedup vs baseline: 1.7860x; 1.7860x over previous
//
#include <hip/hip_runtime.h>
#include <hip/hip_bf16.h>

typedef __bf16 bf16;
typedef __attribute__((ext_vector_type(8))) __bf16 bf16x8;
typedef __attribute__((ext_vector_type(4))) __bf16 bf16x4;
typedef __attribute__((ext_vector_type(4))) float f32x4;

// Problem constants: N=4, T=S=4096, D=256, causal, single head.

static __device__ __forceinline__ unsigned swz(unsigned off, unsigned row) {
  return off ^ ((row & 7u) << 4);
}

// ---------------------------------------------------------------------------
// Input-dtype detector (wave-parallel): bf16 pairs vs fp32 words.
// ---------------------------------------------------------------------------
__global__ void detect_dtype_kernel(const unsigned* __restrict__ q, int* __restrict__ flag) {
  int t = threadIdx.x;  // 64 threads
  int cnt = 0;
  for (int i = t; i < 256; i += 64) {
    unsigned ex = (q[i] >> 7) & 0xFFu;
    cnt += (ex >= 100u && ex <= 140u) ? 1 : 0;
  }
  #pragma unroll
  for (int off = 32; off; off >>= 1) cnt += __shfl_down(cnt, off);
  if (t == 0) *flag = (cnt >= 200) ? 1 : 0;
}

// ---------------------------------------------------------------------------
// Projection GEMM, ROUND 10: 64x128 output tile (was 64x64) — halves X
// re-reads (4 j-tiles -> 2) and doubles MFMA per barrier window (8 -> 16
// per wave per K-chunk). K in 4 chunks of 64, reg-staged async split.
// LDS 24KB (A 8KB + W 16KB). NO min-waves bound (round-6 spill lesson).
// ---------------------------------------------------------------------------
__global__ __launch_bounds__(256) void proj_kernel(
    const void* __restrict__ xq, const void* __restrict__ xk, const void* __restrict__ xv,
    const void* __restrict__ Wq, const void* __restrict__ bq,
    const void* __restrict__ Wk, const void* __restrict__ bk,
    const void* __restrict__ Wv, const void* __restrict__ bv,
    bf16* __restrict__ Qo, bf16* __restrict__ Ko, bf16* __restrict__ Vt,
    const int* __restrict__ flagp)
{
  const int proj = blockIdx.z;
  const void* X  = proj == 0 ? xq : (proj == 1 ? xk : xv);
  const void* W  = proj == 0 ? Wq : (proj == 1 ? Wk : Wv);
  const void* Bp = proj == 0 ? bq : (proj == 1 ? bk : bv);
  const int i0 = blockIdx.x * 64;
  const int j0 = blockIdx.y * 128;
  const int isbf = *flagp;

  __shared__ __align__(16) char lds[24576];
  char* A_lds = lds;          // 64 x 64 bf16 = 8KB, swizzled, row stride 128B
  char* W_lds = lds + 8192;   // 128 x 64 bf16 = 16KB, swizzled, row stride 128B
  const int t = threadIdx.x;

  f32x4 af32[4], wf32[8];
  bf16x8 ab16[2], wb16[4];

  auto load_chunk = [&](int kc) {
    if (isbf) {
      #pragma unroll
      for (int i = 0; i < 2; ++i) {
        int cidx = t + i * 256;
        int row = cidx >> 3, c8 = cidx & 7;
        ab16[i] = *(const bf16x8*)((const char*)X + ((size_t)(i0 + row) << 9) + (kc << 7) + (c8 << 4));
      }
      #pragma unroll
      for (int i = 0; i < 4; ++i) {
        int cidx = t + i * 256;
        int row = cidx >> 3, c8 = cidx & 7;   // row in [0,128)
        wb16[i] = *(const bf16x8*)((const char*)W + ((size_t)(j0 + row) << 9) + (kc << 7) + (c8 << 4));
      }
    } else {
      #pragma unroll
      for (int i = 0; i < 4; ++i) {
        int cidx = t + i * 256;
        int row = cidx >> 4, c4 = cidx & 15;
        af32[i] = *(const f32x4*)((const char*)X + ((size_t)(i0 + row) << 10) + (kc << 8) + (c4 << 4));
      }
      #pragma unroll
      for (int i = 0; i < 8; ++i) {
        int cidx = t + i * 256;
        int row = cidx >> 4, c4 = cidx & 15;  // row in [0,128)
        wf32[i] = *(const f32x4*)((const char*)W + ((size_t)(j0 + row) << 10) + (kc << 8) + (c4 << 4));
      }
    }
  };
  auto write_chunk = [&]() {
    if (isbf) {
      #pragma unroll
      for (int i = 0; i < 2; ++i) {
        int cidx = t + i * 256;
        int row = cidx >> 3, c8 = cidx & 7;
        *(bf16x8*)(A_lds + swz((unsigned)((row << 7) + (c8 << 4)), (unsigned)row)) = ab16[i];
      }
      #pragma unroll
      for (int i = 0; i < 4; ++i) {
        int cidx = t + i * 256;
        int row = cidx >> 3, c8 = cidx & 7;
        *(bf16x8*)(W_lds + swz((unsigned)((row << 7) + (c8 << 4)), (unsigned)row)) = wb16[i];
      }
    } else {
      #pragma unroll
      for (int i = 0; i < 4; ++i) {
        int cidx = t + i * 256;
        int row = cidx >> 4, c4 = cidx & 15;
        bf16x4 ha = { (bf16)af32[i][0], (bf16)af32[i][1], (bf16)af32[i][2], (bf16)af32[i][3] };
        *(bf16x4*)(A_lds + swz((unsigned)((row << 7) + (c4 << 3)), (unsigned)row)) = ha;
      }
      #pragma unroll
      for (int i = 0; i < 8; ++i) {
        int cidx = t + i * 256;
        int row = cidx >> 4, c4 = cidx & 15;
        bf16x4 hw = { (bf16)wf32[i][0], (bf16)wf32[i][1], (bf16)wf32[i][2], (bf16)wf32[i][3] };
        *(bf16x4*)(W_lds + swz((unsigned)((row << 7) + (c4 << 3)), (unsigned)row)) = hw;
      }
    }
  };

  const int w = t >> 6, l = t & 63, lr = l & 15, lhi = l >> 4;
  const int arow = w * 16 + lr;
  f32x4 acc[8] = {};

  load_chunk(0);
  for (int kc = 0; kc < 4; ++kc) {
    write_chunk();
    if (kc < 3) load_chunk(kc + 1);
    __syncthreads();
    #pragma unroll
    for (int kk = 0; kk < 2; ++kk) {
      bf16x8 af = *(const bf16x8*)(A_lds + swz((unsigned)((arow << 7) + (kk << 6) + (lhi << 4)), (unsigned)arow));
      #pragma unroll
      for (int cb = 0; cb < 8; ++cb) {
        int brow = cb * 16 + lr;
        bf16x8 wf = *(const bf16x8*)(W_lds + swz((unsigned)((brow << 7) + (kk << 6) + (lhi << 4)), (unsigned)brow));
        acc[cb] = __builtin_amdgcn_mfma_f32_16x16x32_bf16(af, wf, acc[cb], 0, 0, 0);
      }
    }
    __syncthreads();
  }

  const float QSCALE = 0.09016844005555646f;  // log2(e) / sqrt(256)
  for (int cb = 0; cb < 8; ++cb) {
    int j = j0 + cb * 16 + lr;
    float bias = isbf ? (float)((const bf16*)Bp)[j] : ((const float*)Bp)[j];
    for (int r = 0; r < 4; ++r) {
      int i = i0 + w * 16 + lhi * 4 + r;   // C layout: col=lane&15, row=(lane>>4)*4+r
      float val = acc[cb][r] + bias;
      if (proj == 0) {
        Qo[((size_t)i << 8) + j] = (bf16)(val * QSCALE);
      } else if (proj == 1) {
        Ko[((size_t)i << 8) + j] = (bf16)val;
      } else {
        int n = i >> 12, s = i & 4095;
        Vt[((size_t)n << 20) + ((size_t)j << 12) + s] = (bf16)val;
      }
    }
  }
}

// ---------------------------------------------------------------------------
// Split-KV flash attention (causal), ~uniform 24-tile chunks (204/batch).
// ROUND 7 FIX (pending measurement): no min-waves launch bound — round 6's
// (256,3) capped VGPR at 84 and spilled o[]/staging to scratch
// (FETCH 68MB->637MB, 2x slowdown). Let VGPR float.
// BYTE-IDENTICAL to rounds 7-9 submission (correctness proven in round 6).
// ---------------------------------------------------------------------------
__global__ __launch_bounds__(256) void attn_kernel(
    const bf16* __restrict__ Q, const bf16* __restrict__ K,
    const bf16* __restrict__ Vt, bf16* __restrict__ Opart, float* __restrict__ wrow)
{
  __shared__ __align__(16) char lds[36864];
  char* K_lds  = lds;            // 32 x 256 bf16 = 16KB (swizzled)
  char* V_lds  = lds + 16384;    // 256 x 32 bf16 = 16KB (Vt layout, swizzled)
  char* P_base = lds + 32768;    // 4 waves x 1KB

  const int n  = blockIdx.y;
  // bijective XCD swizzle over 204 = 8*25+4 (m204 variant)
  const int bx  = blockIdx.x;
  const int xcd = bx & 7, idx = bx >> 3;
  const int e   = (xcd < 4 ? xcd * 26 : 104 + (xcd - 4) * 25) + idx;
  int g = 0;
  #pragma unroll
  for (int gg = 1; gg <= 5; ++gg) if (e >= 6 * gg * (gg + 1)) g = gg;
  const int r_   = e - 6 * g * (g + 1);
  const int nc   = g + 1;
  const int qoff = r_ / nc;
  const int qi   = 12 * g + qoff;
  const int c    = r_ - qoff * nc;
  const int q0   = qi * 64;
  const int t32  = (qi + 1) * 2;            // 32-wide KV tiles for this q-tile
  const int it0  = c * t32 / nc, it1 = (c + 1) * t32 / nc;

  const int t = threadIdx.x, w = t >> 6, l = t & 63, lr = l & 15, lhi = l >> 4;
  const bf16* Qb = Q  + ((size_t)n << 20);
  const bf16* Kb = K  + ((size_t)n << 20);
  const bf16* Vb = Vt + ((size_t)n << 20);
  char* myP = P_base + (w << 10);

  // per-thread staging offsets (constant across iterations)
  unsigned gofK[4], lofK[4], gofV[4], lofV[4];
  #pragma unroll
  for (int i = 0; i < 4; ++i) {
    int cidx = t + i * 256;
    int row = cidx >> 5, koff = (cidx & 31) << 4;
    gofK[i] = (unsigned)((row << 9) + koff);
    lofK[i] = swz((unsigned)((row << 9) + koff), (unsigned)row);
    int d = cidx >> 2, soff = (cidx & 3) << 4;
    gofV[i] = (unsigned)((d << 13) + soff);
    lofV[i] = swz((unsigned)((d << 6) + soff), (unsigned)d);
  }
  bf16x8 kst[4], vst[4];
  auto stage_load = [&](int s0) {
    #pragma unroll
    for (int i = 0; i < 4; ++i)
      kst[i] = *(const bf16x8*)((const char*)Kb + (unsigned)(s0 << 9) + gofK[i]);
    #pragma unroll
    for (int i = 0; i < 4; ++i)
      vst[i] = *(const bf16x8*)((const char*)Vb + (unsigned)(s0 << 1) + gofV[i]);
  };

  bf16x8 qf[8];
  {
    int qrow = q0 + w * 16 + lr;
    #pragma unroll
    for (int kb = 0; kb < 8; ++kb)
      qf[kb] = *(const bf16x8*)((const char*)Qb + ((size_t)qrow << 9) + (kb << 6) + (lhi << 4));
  }
  f32x4 o[16] = {};
  float m[4]    = { -3e38f, -3e38f, -3e38f, -3e38f };
  float lsum[4] = { 0.f, 0.f, 0.f, 0.f };

  stage_load(it0 << 5);
  for (int it = it0; it < it1; ++it) {
    // write staged regs -> LDS, then issue next tile's loads (overlap compute)
    #pragma unroll
    for (int i = 0; i < 4; ++i) *(bf16x8*)(K_lds + lofK[i]) = kst[i];
    #pragma unroll
    for (int i = 0; i < 4; ++i) *(bf16x8*)(V_lds + lofV[i]) = vst[i];
    if (it + 1 < it1) stage_load((it + 1) << 5);
    __syncthreads();

    const int s0 = it << 5;
    // S = Q K^T (16x32 per wave), scale folded into Q (base-2)
    f32x4 sacc[2];
    #pragma unroll
    for (int cb = 0; cb < 2; ++cb) {
      f32x4 a = {};
      #pragma unroll
      for (int kb = 0; kb < 8; ++kb) {
        int srow = cb * 16 + lr;
        bf16x8 kf = *(const bf16x8*)(K_lds + swz((unsigned)((srow << 9) + (kb << 6) + (lhi << 4)), (unsigned)srow));
        a = __builtin_amdgcn_mfma_f32_16x16x32_bf16(qf[kb], kf, a, 0, 0, 0);
      }
      sacc[cb] = a;
    }

    // causal mask near the diagonal band only
    if (s0 + 31 > q0 + w * 16) {
      #pragma unroll
      for (int cb = 0; cb < 2; ++cb)
        for (int r = 0; r < 4; ++r) {
          int s_ = s0 + cb * 16 + lr;
          int q_ = q0 + w * 16 + lhi * 4 + r;
          if (s_ > q_) sacc[cb][r] = -3e38f;
        }
    }

    // online softmax (base 2), wave-parallel 16-group reduce
    float pm[4];
    #pragma unroll
    for (int r = 0; r < 4; ++r) pm[r] = fmaxf(sacc[0][r], sacc[1][r]);
    #pragma unroll
    for (int off = 1; off < 16; off <<= 1)
      for (int r = 0; r < 4; ++r) pm[r] = fmaxf(pm[r], __shfl_xor(pm[r], off));

    // defer-max (T13): rescale only when a row max grew past m+8 (log2 units)
    unsigned long long need = __ballot((pm[0] > m[0] + 8.f) | (pm[1] > m[1] + 8.f) |
                                       (pm[2] > m[2] + 8.f) | (pm[3] > m[3] + 8.f));
    if (need) {
      float alpha[4];
      #pragma unroll
      for (int r = 0; r < 4; ++r) {
        float mn = fmaxf(m[r], pm[r]);
        alpha[r] = exp2f(m[r] - mn);
        m[r] = mn;
        lsum[r] *= alpha[r];
      }
      #pragma unroll
      for (int db = 0; db < 16; ++db)
        for (int r = 0; r < 4; ++r) o[db][r] *= alpha[r];
    }

    float ps[4] = {};
    #pragma unroll
    for (int cb = 0; cb < 2; ++cb)
      for (int r = 0; r < 4; ++r) {
        float p = exp2f(sacc[cb][r] - m[r]);
        sacc[cb][r] = p;
        ps[r] += p;
      }
    #pragma unroll
    for (int off = 1; off < 16; off <<= 1)
      for (int r = 0; r < 4; ++r) ps[r] += __shfl_xor(ps[r], off);
    #pragma unroll
    for (int r = 0; r < 4; ++r) lsum[r] += ps[r];

    // P (C layout) -> per-wave LDS tile -> A-fragment layout
    #pragma unroll
    for (int cb = 0; cb < 2; ++cb)
      for (int r = 0; r < 4; ++r) {
        int prow = lhi * 4 + r, pcol = cb * 16 + lr;
        *(bf16*)(myP + swz((unsigned)((prow << 6) + (pcol << 1)), (unsigned)prow)) = (bf16)sacc[cb][r];
      }
    asm volatile("s_waitcnt lgkmcnt(0)" ::: "memory");
    __builtin_amdgcn_sched_barrier(0);

    bf16x8 pf = *(const bf16x8*)(myP + swz((unsigned)((lr << 6) + (lhi << 4)), (unsigned)lr));
    #pragma unroll
    for (int db = 0; db < 16; ++db) {
      int drow = db * 16 + lr;
      bf16x8 vf = *(const bf16x8*)(V_lds + swz((unsigned)((drow << 6) + (lhi << 4)), (unsigned)drow));
      o[db] = __builtin_amdgcn_mfma_f32_16x16x32_bf16(pf, vf, o[db], 0, 0, 0);
    }
    __syncthreads();
  }

  // epilogue: normalized partial (bf16) + per-row combine weight w = m + log2(l)
  float invl[4];
  #pragma unroll
  for (int r = 0; r < 4; ++r) invl[r] = 1.f / lsum[r];
  bf16* Ob = Opart + (size_t)(n * 204 + e) * 16384;
  for (int db = 0; db < 16; ++db) {
    int col = db * 16 + lr;
    for (int r = 0; r < 4; ++r) {
      int row = w * 16 + lhi * 4 + r;
      Ob[row * 256 + col] = (bf16)(o[db][r] * invl[r]);
    }
  }
  if (lr == 0) {
    #pragma unroll
    for (int r = 0; r < 4; ++r) {
      int row = w * 16 + lhi * 4 + r;
      wrow[(n * 204 + e) * 64 + row] = m[r] + log2f(lsum[r]);
    }
  }
}

// ---------------------------------------------------------------------------
// Combine (unchanged from round 6).
// ---------------------------------------------------------------------------
__global__ __launch_bounds__(256) void combine_kernel(
    const bf16* __restrict__ Opart, const float* __restrict__ wrow,
    float* __restrict__ out)
{
  const int bx = blockIdx.x, n = blockIdx.y;
  const int qi = bx >> 2, rowbase = (bx & 3) << 4;
  const int g  = qi / 12;                    // 0..5
  const int nc = g + 1;
  const int off = 6 * g * (g + 1) + (qi - 12 * g) * nc;
  const int t = threadIdx.x;
  const int row  = rowbase + (t >> 4);       // tile-local q-row
  const int col0 = (t & 15) << 4;            // 16 cols per thread
  const size_t pbase = (size_t)(n * 204 + off);

  float u[6];
  float Wm = -3e38f;
  #pragma unroll
  for (int i = 0; i < 6; ++i) {
    u[i] = (i < nc) ? wrow[(pbase + i) * 64 + row] : -3e38f;
    Wm = fmaxf(Wm, u[i]);
  }
  float denom = 0.f;
  #pragma unroll
  for (int i = 0; i < 6; ++i) { u[i] = (i < nc) ? exp2f(u[i] - Wm) : 0.f; denom += u[i]; }
  float inv = 1.f / denom;

  float a[16] = {};
  #pragma unroll
  for (int i = 0; i < 6; ++i) {
    if (i < nc) {
      float ui = u[i] * inv;
      const bf16* p = Opart + (pbase + i) * 16384 + row * 256 + col0;
      bf16x8 v0 = *(const bf16x8*)(p);
      bf16x8 v1 = *(const bf16x8*)(p + 8);
      #pragma unroll
      for (int j = 0; j < 8; ++j) { a[j] += ui * (float)v0[j]; a[8 + j] += ui * (float)v1[j]; }
    }
  }
  float* op = out + ((size_t)n << 20) + ((size_t)(qi * 64 + row) << 8) + col0;
  #pragma unroll
  for (int j2 = 0; j2 < 4; ++j2) {
    f32x4 vv = { a[j2 * 4], a[j2 * 4 + 1], a[j2 * 4 + 2], a[j2 * 4 + 3] };
    *(f32x4*)(op + j2 * 4) = vv;
  }
}

extern "C" void kernel_launch(void* const* d_in, const int* in_sizes, int n_in,
                              void* d_out, int out_size, void* d_ws, size_t ws_size,
                              hipStream_t stream) {
  const void* q_in = d_in[0];
  const void* k_in = d_in[1];
  const void* v_in = d_in[2];
  // d_in[3] = attn_mask: causal tril, hardcoded
  const void* Wq = d_in[4]; const void* bq = d_in[5];
  const void* Wk = d_in[6]; const void* bk = d_in[7];
  const void* Wv = d_in[8]; const void* bv = d_in[9];

  char* ws = (char*)d_ws;
  bf16*  Qw    = (bf16*)(ws);                              // 8 MB
  bf16*  Kw    = (bf16*)(ws + (size_t)(8  << 20));         // 8 MB
  bf16*  Vtw   = (bf16*)(ws + (size_t)(16 << 20));         // 8 MB, [n][d][s]
  int*   flag  = (int*) (ws + (size_t)(24 << 20));         // 4 B
  float* wrow  = (float*)(ws + (size_t)(24 << 20) + 4096); // 4*204*64*4 = 209 KB
  bf16*  Opart = (bf16*)(ws + (size_t)(25 << 20));         // 4*204*32KB = 26.7 MB

  detect_dtype_kernel<<<1, 64, 0, stream>>>((const unsigned*)q_in, flag);
  proj_kernel<<<dim3(256, 2, 3), 256, 0, stream>>>(q_in, k_in, v_in,
                                                   Wq, bq, Wk, bk, Wv, bv,
                                                   Qw, Kw, Vtw, flag);
  attn_kernel<<<dim3(204, 4), 256, 0, stream>>>(Qw, Kw, Vtw, Opart, wrow);
  combine_kernel<<<dim3(256, 4), 256, 0, stream>>>(Opart, wrow, (float*)d_out);
}